// Round 3
// baseline (437.573 us; speedup 1.0000x reference)
//
#include <hip/hip_runtime.h>

#define AS1 __attribute__((address_space(1)))
#define AS3 __attribute__((address_space(3)))
#define NSLOT 8
#define CHUNK 256
#define PPB 1024

__device__ __forceinline__ void gld_lds16(const float* g, float* l) {
  __builtin_amdgcn_global_load_lds((const AS1 void*)g, (AS3 void*)l, 16, 0, 0);
}
__device__ __forceinline__ void gld_lds4(const void* g, void* l) {
  __builtin_amdgcn_global_load_lds((const AS1 void*)g, (AS3 void*)l, 4, 0, 0);
}

#define WAITVM11 do { asm volatile("s_waitcnt vmcnt(11)" ::: "memory"); __builtin_amdgcn_sched_barrier(0); } while (0)
#define WAITVM0  do { asm volatile("s_waitcnt vmcnt(0)" ::: "memory"); __builtin_amdgcn_sched_barrier(0); } while (0)
#define WAITLGKM do { asm volatile("s_waitcnt lgkmcnt(0)" ::: "memory"); __builtin_amdgcn_sched_barrier(0); } while (0)
#define BAR __builtin_amdgcn_s_barrier()

__global__ void zero_k(float* __restrict__ p, int n) {
  int i = blockIdx.x * blockDim.x + threadIdx.x;
  if (i < n) p[i] = 0.f;
}

// Streams r + ri once. Outputs: zb (u8 argmax), wpair (float2 gated resp),
// pig (global partial sums of ri columns).
__global__ __launch_bounds__(256) void prep_k(
    const float* __restrict__ r, const float* __restrict__ ri,
    unsigned char* __restrict__ zb, float* __restrict__ wpairf,
    float* __restrict__ pig, int n)
{
  __shared__ float lpi[256][33];
  float acc[32];
#pragma unroll
  for (int c = 0; c < 32; ++c) acc[c] = 0.f;

  for (int i = blockIdx.x * blockDim.x + threadIdx.x; i < n;
       i += gridDim.x * blockDim.x) {
    const float4* rr = (const float4*)(r + (size_t)i * 16);
    float4 a0 = rr[0], a1 = rr[1], a2 = rr[2], a3 = rr[3];
    float best = a0.x; int z = 0;
#define CHK(v, c) if ((v) > best) { best = (v); z = (c); }
    CHK(a0.y,1) CHK(a0.z,2) CHK(a0.w,3)
    CHK(a1.x,4) CHK(a1.y,5) CHK(a1.z,6) CHK(a1.w,7)
    CHK(a2.x,8) CHK(a2.y,9) CHK(a2.z,10) CHK(a2.w,11)
    CHK(a3.x,12) CHK(a3.y,13) CHK(a3.z,14) CHK(a3.w,15)
#undef CHK
    const float4* qq = (const float4*)(ri + (size_t)i * 32);
    float4 v0 = qq[0], v1 = qq[1], v2 = qq[2], v3 = qq[3];
    float4 v4 = qq[4], v5 = qq[5], v6 = qq[6], v7 = qq[7];
    acc[0]+=v0.x; acc[1]+=v0.y; acc[2]+=v0.z; acc[3]+=v0.w;
    acc[4]+=v1.x; acc[5]+=v1.y; acc[6]+=v1.z; acc[7]+=v1.w;
    acc[8]+=v2.x; acc[9]+=v2.y; acc[10]+=v2.z; acc[11]+=v2.w;
    acc[12]+=v3.x; acc[13]+=v3.y; acc[14]+=v3.z; acc[15]+=v3.w;
    acc[16]+=v4.x; acc[17]+=v4.y; acc[18]+=v4.z; acc[19]+=v4.w;
    acc[20]+=v5.x; acc[21]+=v5.y; acc[22]+=v5.z; acc[23]+=v5.w;
    acc[24]+=v6.x; acc[25]+=v6.y; acc[26]+=v6.z; acc[27]+=v6.w;
    acc[28]+=v7.x; acc[29]+=v7.y; acc[30]+=v7.z; acc[31]+=v7.w;
    // select ri[2z], ri[2z+1] from registers (cndmask tree)
    int q = z >> 1;
    float4 sel = q < 4 ? (q < 2 ? (q == 0 ? v0 : v1) : (q == 2 ? v2 : v3))
                       : (q < 6 ? (q == 4 ? v4 : v5) : (q == 6 ? v6 : v7));
    float w0 = (z & 1) ? sel.z : sel.x;
    float w1 = (z & 1) ? sel.w : sel.y;
    zb[i] = (unsigned char)z;
    *(float2*)&wpairf[(size_t)i * 2] = make_float2(w0, w1);
  }

#pragma unroll
  for (int c = 0; c < 32; ++c) lpi[threadIdx.x][c] = acc[c];
  __syncthreads();
  if (threadIdx.x < 32) {
    float s = 0.f;
    for (int t = 0; t < 256; ++t) s += lpi[t][threadIdx.x];
    atomicAdd(&pig[threadIdx.x], s);
  }
}

// Streams X sequentially (double-buffered global_load_lds, counted vmcnt).
// Per 256-point chunk: build per-cluster lists from staged z, then each of
// 4 waves accumulates its 4 clusters' points (lane = 4x4 (d1,d2) tile).
__global__ __launch_bounds__(256, 2) void mstep_k(
    const float* __restrict__ X, const unsigned char* __restrict__ zb,
    const float* __restrict__ wpairf,
    float* __restrict__ m2s, float* __restrict__ muss, float* __restrict__ dns,
    int n)
{
  __shared__ float xls[2][CHUNK * 32];          // 64 KB
  __shared__ float wls[2][CHUNK * 2];           // 4 KB
  __shared__ unsigned char zls[2][CHUNK];       // 512 B
  __shared__ unsigned char list[2][16][CHUNK];  // 8 KB
  __shared__ int lcnt[2][16];

  const int t = threadIdx.x;
  const int wv = t >> 6;
  const int l = t & 63;
  const int g1 = l >> 3;
  const int g2 = l & 7;
  const int bs = blockIdx.x * PPB;
  const int be = min(bs + PPB, n);
  const int nsc = (be - bs + CHUNK - 1) / CHUNK;
  const int slot = blockIdx.x & (NSLOT - 1);

  float acc[4][2][4][4];
  float mm[4][2][4];
  float dnv[4][2];
#pragma unroll
  for (int c = 0; c < 4; ++c) {
#pragma unroll
    for (int s = 0; s < 2; ++s) {
      dnv[c][s] = 0.f;
#pragma unroll
      for (int j = 0; j < 4; ++j) mm[c][s][j] = 0.f;
#pragma unroll
      for (int i1 = 0; i1 < 4; ++i1)
#pragma unroll
        for (int i2 = 0; i2 < 4; ++i2) acc[c][s][i1][i2] = 0.f;
    }
  }

  auto stage = [&](int i) {
    const int c0 = bs + i * CHUNK;
    const int buf = i & 1;
    // X rows: wave wv covers rows [wv*64, wv*64+64); 8 instr x 1KB, contiguous
#pragma unroll
    for (int q = 0; q < 8; ++q) {
      int gi = c0 + wv * 64 + q * 8 + g1;
      if (gi > n - 1) gi = n - 1;
      gld_lds16(X + (size_t)gi * 32 + (g2 << 2), &xls[buf][(wv * 64 + q * 8) * 32]);
    }
    // w pairs: 512 floats; wave wv covers [wv*128, +128) via 2 instr
#pragma unroll
    for (int j = 0; j < 2; ++j) {
      int fi = wv * 128 + j * 64;
      long gfi = (long)c0 * 2 + fi + l;
      if (gfi > 2L * n - 1) gfi = 2L * n - 1;
      gld_lds4(wpairf + gfi, &wls[buf][fi]);
    }
    // z bytes: 256 B; all 4 waves issue identical load (benign dup) to keep
    // per-wave vmcnt counts equal (11)
    gld_lds4(zb + c0 + 4 * l, &zls[buf][0]);
  };

  stage(0);
  if (t < 16) lcnt[0][t] = 0;

  for (int i = 0; i < nsc; ++i) {
    const int buf = i & 1;
    if (i + 1 < nsc) { stage(i + 1); WAITVM11; } else { WAITVM0; }
    WAITLGKM;
    BAR;  // A: stage(i) data + lcnt[buf] zero visible

    int rem = be - (bs + i * CHUNK); if (rem > CHUNK) rem = CHUNK;
    if (t < rem) {
      int zv = zls[buf][t];
      int pos = atomicAdd(&lcnt[buf][zv], 1);
      list[buf][zv][pos] = (unsigned char)t;
    }
    if (t < 16) lcnt[buf ^ 1][t] = 0;
    WAITLGKM;
    BAR;  // B: lists ready

    const float* xb = xls[buf];
    const float* wb = wls[buf];
#pragma unroll
    for (int c = 0; c < 4; ++c) {
      const int kk = wv * 4 + c;
      const int cnt = lcnt[buf][kk];
      const unsigned char* lk = list[buf][kk];
      if (cnt > 0) {
        int p = lk[0];
        float2 wp = *(const float2*)&wb[p * 2];
        float4 x1 = *(const float4*)&xb[p * 32 + g1 * 4];
        float4 x2 = *(const float4*)&xb[p * 32 + g2 * 4];
        for (int j = 0; j < cnt; ++j) {
          int jn = j + 1 < cnt ? j + 1 : j;
          int pn = lk[jn];
          float2 wpn = *(const float2*)&wb[pn * 2];
          float4 x1n = *(const float4*)&xb[pn * 32 + g1 * 4];
          float4 x2n = *(const float4*)&xb[pn * 32 + g2 * 4];
          float w0 = wp.x, w1 = wp.y;
          float xv1[4] = {x1.x, x1.y, x1.z, x1.w};
          float xv2[4] = {x2.x, x2.y, x2.z, x2.w};
#pragma unroll
          for (int j4 = 0; j4 < 4; ++j4) {
            mm[c][0][j4] += w0 * xv2[j4];
            mm[c][1][j4] += w1 * xv2[j4];
          }
#pragma unroll
          for (int i1 = 0; i1 < 4; ++i1) {
            float a0 = w0 * xv1[i1], a1 = w1 * xv1[i1];
#pragma unroll
            for (int i2 = 0; i2 < 4; ++i2) {
              acc[c][0][i1][i2] += a0 * xv2[i2];
              acc[c][1][i1][i2] += a1 * xv2[i2];
            }
          }
          dnv[c][0] += w0; dnv[c][1] += w1;
          wp = wpn; x1 = x1n; x2 = x2n;
        }
      }
    }
    WAITLGKM;
    BAR;  // C: all reads of buf[i&1] complete
  }

  // merge: slot-spread global atomics (each wave owns distinct comps)
#pragma unroll
  for (int c = 0; c < 4; ++c) {
    const int comp0 = (wv * 4 + c) * 2;
#pragma unroll
    for (int s = 0; s < 2; ++s) {
      float* dst = m2s + ((size_t)slot * 32 + comp0 + s) * 1024;
#pragma unroll
      for (int i1 = 0; i1 < 4; ++i1)
#pragma unroll
        for (int i2 = 0; i2 < 4; ++i2)
          atomicAdd(&dst[(g1 * 4 + i1) * 32 + g2 * 4 + i2], acc[c][s][i1][i2]);
      if (g1 == 0) {
#pragma unroll
        for (int j = 0; j < 4; ++j)
          atomicAdd(&muss[((size_t)slot * 32 + comp0 + s) * 32 + g2 * 4 + j],
                    mm[c][s][j]);
      }
      if (l == 0) atomicAdd(&dns[slot * 32 + comp0 + s], dnv[c][s]);
    }
  }
}

__global__ __launch_bounds__(256) void finalize_k(
    const float* __restrict__ pig, const float* __restrict__ dns,
    const float* __restrict__ muss, const float* __restrict__ m2s,
    float* __restrict__ out, int n)
{
  const int c = blockIdx.x;   // component 0..31
  const int t = threadIdx.x;
  __shared__ float mu[32];
  float dsum = 0.f;
#pragma unroll
  for (int s = 0; s < NSLOT; ++s) dsum += dns[s * 32 + c];
  float safe = fmaxf(dsum, 1e-10f);
  if (t < 32) {
    float m = 0.f;
#pragma unroll
    for (int s = 0; s < NSLOT; ++s) m += muss[((size_t)s * 32 + c) * 32 + t];
    m /= safe;
    mu[t] = m;
    out[32 + c * 32 + t] = m;                       // mus
  }
  if (c == 0 && t < 32) out[t] = pig[t] / (float)n; // pi
  __syncthreads();
#pragma unroll
  for (int q = 0; q < 4; ++q) {
    int e = t * 4 + q;
    float m2 = 0.f;
#pragma unroll
    for (int s = 0; s < NSLOT; ++s) m2 += m2s[((size_t)s * 32 + c) * 1024 + e];
    out[32 + 1024 + c * 1024 + e] = m2 / safe - mu[e >> 5] * mu[e & 31];
  }
}

extern "C" void kernel_launch(void* const* d_in, const int* in_sizes, int n_in,
                              void* d_out, int out_size, void* d_ws, size_t ws_size,
                              hipStream_t stream) {
  const float* X  = (const float*)d_in[0];
  const float* r  = (const float*)d_in[1];
  const float* ri = (const float*)d_in[2];
  float* out = (float*)d_out;
  const int n = in_sizes[0] / 32;

  // ws layout (floats unless noted)
  float* wpair = (float*)d_ws;                         // 2n
  float* m2s   = wpair + 2 * (size_t)n;                // NSLOT*32*1024
  float* muss  = m2s + (size_t)NSLOT * 32 * 1024;      // NSLOT*32*32
  float* dns   = muss + NSLOT * 32 * 32;               // NSLOT*32
  float* pig   = dns + NSLOT * 32;                     // 32
  unsigned char* zbuf = (unsigned char*)(pig + 32);    // n + 256 pad

  const int zero_words = NSLOT * 32 * 1024 + NSLOT * 32 * 32 + NSLOT * 32 + 32;
  zero_k<<<(zero_words + 255) / 256, 256, 0, stream>>>(m2s, zero_words);
  prep_k<<<1024, 256, 0, stream>>>(r, ri, zbuf, wpair, pig, n);
  const int grid_m = (n + PPB - 1) / PPB;
  mstep_k<<<grid_m, 256, 0, stream>>>(X, zbuf, wpair, m2s, muss, dns, n);
  finalize_k<<<32, 256, 0, stream>>>(pig, dns, muss, m2s, out, n);
}

// Round 4
// 366.043 us; speedup vs baseline: 1.1954x; 1.1954x over previous
//
#include <hip/hip_runtime.h>

#define AS1 __attribute__((address_space(1)))
#define AS3 __attribute__((address_space(3)))
#define NSLOT 8
#define CHUNK 256
#define PPB 1024

__device__ __forceinline__ void gld_lds16(const float* g, float* l) {
  __builtin_amdgcn_global_load_lds((const AS1 void*)g, (AS3 void*)l, 16, 0, 0);
}
__device__ __forceinline__ void gld_lds4(const void* g, void* l) {
  __builtin_amdgcn_global_load_lds((const AS1 void*)g, (AS3 void*)l, 4, 0, 0);
}

#define WAITVM6  do { asm volatile("s_waitcnt vmcnt(6)" ::: "memory"); __builtin_amdgcn_sched_barrier(0); } while (0)
#define WAITVM0  do { asm volatile("s_waitcnt vmcnt(0)" ::: "memory"); __builtin_amdgcn_sched_barrier(0); } while (0)
#define WAITLGKM do { asm volatile("s_waitcnt lgkmcnt(0)" ::: "memory"); __builtin_amdgcn_sched_barrier(0); } while (0)
#define BAR __builtin_amdgcn_s_barrier()

__global__ void zero_k(float* __restrict__ p, int n) {
  int i = blockIdx.x * blockDim.x + threadIdx.x;
  if (i < n) p[i] = 0.f;
}

// Streams r + ri once. Outputs: zb (u8 argmax), wpair (float2 gated resp),
// pig (global partial sums of ri columns).
__global__ __launch_bounds__(256) void prep_k(
    const float* __restrict__ r, const float* __restrict__ ri,
    unsigned char* __restrict__ zb, float* __restrict__ wpairf,
    float* __restrict__ pig, int n)
{
  __shared__ float lpi[256][33];
  float acc[32];
#pragma unroll
  for (int c = 0; c < 32; ++c) acc[c] = 0.f;

  for (int i = blockIdx.x * blockDim.x + threadIdx.x; i < n;
       i += gridDim.x * blockDim.x) {
    const float4* rr = (const float4*)(r + (size_t)i * 16);
    float4 a0 = rr[0], a1 = rr[1], a2 = rr[2], a3 = rr[3];
    float best = a0.x; int z = 0;
#define CHK(v, c) if ((v) > best) { best = (v); z = (c); }
    CHK(a0.y,1) CHK(a0.z,2) CHK(a0.w,3)
    CHK(a1.x,4) CHK(a1.y,5) CHK(a1.z,6) CHK(a1.w,7)
    CHK(a2.x,8) CHK(a2.y,9) CHK(a2.z,10) CHK(a2.w,11)
    CHK(a3.x,12) CHK(a3.y,13) CHK(a3.z,14) CHK(a3.w,15)
#undef CHK
    const float4* qq = (const float4*)(ri + (size_t)i * 32);
    float4 v0 = qq[0], v1 = qq[1], v2 = qq[2], v3 = qq[3];
    float4 v4 = qq[4], v5 = qq[5], v6 = qq[6], v7 = qq[7];
    acc[0]+=v0.x; acc[1]+=v0.y; acc[2]+=v0.z; acc[3]+=v0.w;
    acc[4]+=v1.x; acc[5]+=v1.y; acc[6]+=v1.z; acc[7]+=v1.w;
    acc[8]+=v2.x; acc[9]+=v2.y; acc[10]+=v2.z; acc[11]+=v2.w;
    acc[12]+=v3.x; acc[13]+=v3.y; acc[14]+=v3.z; acc[15]+=v3.w;
    acc[16]+=v4.x; acc[17]+=v4.y; acc[18]+=v4.z; acc[19]+=v4.w;
    acc[20]+=v5.x; acc[21]+=v5.y; acc[22]+=v5.z; acc[23]+=v5.w;
    acc[24]+=v6.x; acc[25]+=v6.y; acc[26]+=v6.z; acc[27]+=v6.w;
    acc[28]+=v7.x; acc[29]+=v7.y; acc[30]+=v7.z; acc[31]+=v7.w;
    // select ri[2z], ri[2z+1] from registers (cndmask tree)
    int q = z >> 1;
    float4 sel = q < 4 ? (q < 2 ? (q == 0 ? v0 : v1) : (q == 2 ? v2 : v3))
                       : (q < 6 ? (q == 4 ? v4 : v5) : (q == 6 ? v6 : v7));
    float w0 = (z & 1) ? sel.z : sel.x;
    float w1 = (z & 1) ? sel.w : sel.y;
    zb[i] = (unsigned char)z;
    *(float2*)&wpairf[(size_t)i * 2] = make_float2(w0, w1);
  }

#pragma unroll
  for (int c = 0; c < 32; ++c) lpi[threadIdx.x][c] = acc[c];
  __syncthreads();
  if (threadIdx.x < 32) {
    float s = 0.f;
    for (int t = 0; t < 256; ++t) s += lpi[t][threadIdx.x];
    atomicAdd(&pig[threadIdx.x], s);
  }
}

// Streams X sequentially (double-buffered global_load_lds, counted vmcnt(6)).
// 8 waves/block; per 256-point chunk build per-cluster lists from staged z,
// then each wave accumulates its 2 clusters (lane = 4x4 (d1,d2) tile).
// acc = 2 clusters x 2 subcomp x 16 = 64 regs (+mm 16 +dn 4): no spill at 128.
__global__ __launch_bounds__(512, 4) void mstep_k(
    const float* __restrict__ X, const unsigned char* __restrict__ zb,
    const float* __restrict__ wpairf,
    float* __restrict__ m2s, float* __restrict__ muss, float* __restrict__ dns,
    int n)
{
  __shared__ float xls[2][CHUNK * 32];          // 64 KB
  __shared__ float wls[2][CHUNK * 2];           // 4 KB
  __shared__ unsigned char zls[2][CHUNK];       // 512 B
  __shared__ unsigned char list[2][16][CHUNK];  // 8 KB
  __shared__ int lcnt[2][16];

  const int t = threadIdx.x;
  const int wv = t >> 6;      // 0..7
  const int l = t & 63;
  const int g1 = l >> 3;
  const int g2 = l & 7;
  const int bs = blockIdx.x * PPB;
  const int be = min(bs + PPB, n);
  const int nsc = (be - bs + CHUNK - 1) / CHUNK;
  const int slot = blockIdx.x & (NSLOT - 1);

  float acc[2][2][4][4];
  float mm[2][2][4];
  float dnv[2][2];
#pragma unroll
  for (int c = 0; c < 2; ++c)
#pragma unroll
    for (int s = 0; s < 2; ++s) {
      dnv[c][s] = 0.f;
#pragma unroll
      for (int j = 0; j < 4; ++j) mm[c][s][j] = 0.f;
#pragma unroll
      for (int i1 = 0; i1 < 4; ++i1)
#pragma unroll
        for (int i2 = 0; i2 < 4; ++i2) acc[c][s][i1][i2] = 0.f;
    }

  auto stage = [&](int i) {
    const int c0 = bs + i * CHUNK;
    const int buf = i & 1;
    // X rows: wave wv covers rows [wv*32, wv*32+32); 4 instr x 1KB contiguous
#pragma unroll
    for (int q = 0; q < 4; ++q) {
      int gi = c0 + wv * 32 + q * 8 + g1;
      if (gi > n - 1) gi = n - 1;
      gld_lds16(X + (size_t)gi * 32 + (g2 << 2), &xls[buf][(wv * 32 + q * 8) * 32]);
    }
    // w pairs: 512 floats; wave wv covers [wv*64, +64) via 1 instr
    {
      long gfi = (long)c0 * 2 + wv * 64 + l;
      if (gfi > 2L * n - 1) gfi = 2L * n - 1;
      gld_lds4(wpairf + gfi, &wls[buf][wv * 64]);
    }
    // z bytes: 256 B; all 8 waves issue identical load (benign dup) to keep
    // per-wave vmcnt uniform (6 per stage)
    gld_lds4(zb + c0 + 4 * l, &zls[buf][0]);
  };

  stage(0);
  if (t < 16) lcnt[0][t] = 0;

  for (int i = 0; i < nsc; ++i) {
    const int buf = i & 1;
    if (i + 1 < nsc) { stage(i + 1); WAITVM6; } else { WAITVM0; }
    WAITLGKM;
    BAR;  // A: stage(i) data + lcnt[buf] zero visible

    int rem = be - (bs + i * CHUNK); if (rem > CHUNK) rem = CHUNK;
    if (t < rem) {
      int zv = zls[buf][t];
      int pos = atomicAdd(&lcnt[buf][zv], 1);
      list[buf][zv][pos] = (unsigned char)t;
    }
    if (t < 16) lcnt[buf ^ 1][t] = 0;
    WAITLGKM;
    BAR;  // B: lists ready

    const float* xb = xls[buf];
    const float* wb = wls[buf];
#pragma unroll
    for (int c = 0; c < 2; ++c) {
      const int kk = wv * 2 + c;
      const int cnt = lcnt[buf][kk];
      const unsigned char* lk = list[buf][kk];
      if (cnt > 0) {
        int p = lk[0];
        float2 wp = *(const float2*)&wb[p * 2];
        float4 x1 = *(const float4*)&xb[p * 32 + g1 * 4];
        float4 x2 = *(const float4*)&xb[p * 32 + g2 * 4];
        for (int j = 0; j < cnt; ++j) {
          int jn = j + 1 < cnt ? j + 1 : j;
          int pn = lk[jn];
          float2 wpn = *(const float2*)&wb[pn * 2];
          float4 x1n = *(const float4*)&xb[pn * 32 + g1 * 4];
          float4 x2n = *(const float4*)&xb[pn * 32 + g2 * 4];
          float w0 = wp.x, w1 = wp.y;
          float xv1[4] = {x1.x, x1.y, x1.z, x1.w};
          float xv2[4] = {x2.x, x2.y, x2.z, x2.w};
#pragma unroll
          for (int j4 = 0; j4 < 4; ++j4) {
            mm[c][0][j4] += w0 * xv2[j4];
            mm[c][1][j4] += w1 * xv2[j4];
          }
#pragma unroll
          for (int i1 = 0; i1 < 4; ++i1) {
            float a0 = w0 * xv1[i1], a1 = w1 * xv1[i1];
#pragma unroll
            for (int i2 = 0; i2 < 4; ++i2) {
              acc[c][0][i1][i2] += a0 * xv2[i2];
              acc[c][1][i1][i2] += a1 * xv2[i2];
            }
          }
          dnv[c][0] += w0; dnv[c][1] += w1;
          wp = wpn; x1 = x1n; x2 = x2n;
        }
      }
    }
    WAITLGKM;
    BAR;  // C: all reads of buf complete before it is restaged
  }

  // merge: slot-spread global atomics (each wave owns distinct comps)
#pragma unroll
  for (int c = 0; c < 2; ++c) {
    const int comp0 = (wv * 2 + c) * 2;
#pragma unroll
    for (int s = 0; s < 2; ++s) {
      float* dst = m2s + ((size_t)slot * 32 + comp0 + s) * 1024;
#pragma unroll
      for (int i1 = 0; i1 < 4; ++i1)
#pragma unroll
        for (int i2 = 0; i2 < 4; ++i2)
          atomicAdd(&dst[(g1 * 4 + i1) * 32 + g2 * 4 + i2], acc[c][s][i1][i2]);
      if (g1 == 0) {
#pragma unroll
        for (int j = 0; j < 4; ++j)
          atomicAdd(&muss[((size_t)slot * 32 + comp0 + s) * 32 + g2 * 4 + j],
                    mm[c][s][j]);
      }
      if (l == 0) atomicAdd(&dns[slot * 32 + comp0 + s], dnv[c][s]);
    }
  }
}

__global__ __launch_bounds__(256) void finalize_k(
    const float* __restrict__ pig, const float* __restrict__ dns,
    const float* __restrict__ muss, const float* __restrict__ m2s,
    float* __restrict__ out, int n)
{
  const int c = blockIdx.x;   // component 0..31
  const int t = threadIdx.x;
  __shared__ float mu[32];
  float dsum = 0.f;
#pragma unroll
  for (int s = 0; s < NSLOT; ++s) dsum += dns[s * 32 + c];
  float safe = fmaxf(dsum, 1e-10f);
  if (t < 32) {
    float m = 0.f;
#pragma unroll
    for (int s = 0; s < NSLOT; ++s) m += muss[((size_t)s * 32 + c) * 32 + t];
    m /= safe;
    mu[t] = m;
    out[32 + c * 32 + t] = m;                       // mus
  }
  if (c == 0 && t < 32) out[t] = pig[t] / (float)n; // pi
  __syncthreads();
#pragma unroll
  for (int q = 0; q < 4; ++q) {
    int e = t * 4 + q;
    float m2 = 0.f;
#pragma unroll
    for (int s = 0; s < NSLOT; ++s) m2 += m2s[((size_t)s * 32 + c) * 1024 + e];
    out[32 + 1024 + c * 1024 + e] = m2 / safe - mu[e >> 5] * mu[e & 31];
  }
}

extern "C" void kernel_launch(void* const* d_in, const int* in_sizes, int n_in,
                              void* d_out, int out_size, void* d_ws, size_t ws_size,
                              hipStream_t stream) {
  const float* X  = (const float*)d_in[0];
  const float* r  = (const float*)d_in[1];
  const float* ri = (const float*)d_in[2];
  float* out = (float*)d_out;
  const int n = in_sizes[0] / 32;

  // ws layout (floats unless noted)
  float* wpair = (float*)d_ws;                         // 2n
  float* m2s   = wpair + 2 * (size_t)n;                // NSLOT*32*1024
  float* muss  = m2s + (size_t)NSLOT * 32 * 1024;      // NSLOT*32*32
  float* dns   = muss + NSLOT * 32 * 32;               // NSLOT*32
  float* pig   = dns + NSLOT * 32;                     // 32
  unsigned char* zbuf = (unsigned char*)(pig + 32);    // n + 256 pad

  const int zero_words = NSLOT * 32 * 1024 + NSLOT * 32 * 32 + NSLOT * 32 + 32;
  zero_k<<<(zero_words + 255) / 256, 256, 0, stream>>>(m2s, zero_words);
  prep_k<<<1024, 256, 0, stream>>>(r, ri, zbuf, wpair, pig, n);
  const int grid_m = (n + PPB - 1) / PPB;
  mstep_k<<<grid_m, 512, 0, stream>>>(X, zbuf, wpair, m2s, muss, dns, n);
  finalize_k<<<32, 256, 0, stream>>>(pig, dns, muss, m2s, out, n);
}